// Round 17
// baseline (105.991 us; speedup 1.0000x reference)
//
#include <hip/hip_runtime.h>
#include <hip/hip_bf16.h>

#define BATCH 2048
#define IDIM  256
#define ODIM  64
#define GRIDN 300

typedef __bf16 bf16x8 __attribute__((ext_vector_type(8)));
typedef float  f32x16 __attribute__((ext_vector_type(16)));
typedef float  f32x4  __attribute__((ext_vector_type(4)));
typedef float  f32x2  __attribute__((ext_vector_type(2)));
typedef unsigned int uint4v __attribute__((ext_vector_type(4)));

// Session rules: NO unions in hot paths (R4/R5/R6 scratch-demotion);
// NO launch_bounds below natural allocation (R8); NO __float2bfloat16 in hot
// loops (R9) -> HW v_cvt_pk_bf16_f32 (asm, proven -8us).
// R17 theory: the 56-58us plateau survived occupancy/barrier/atomic/cache
// variations; the UNVARIED common elements are (a) s_setprio brackets (side-
// effecting intrinsic = scheduling fence; m190 measured it NEGATIVE on
// lockstep GEMM) and (b) 16 inline-asm v_pk_* statements whose register
// constraints pin the schedule (proven perf-neutral as a win). Remove both;
// let the scheduler software-pipeline across iterations.
__device__ __forceinline__ unsigned short f2bf(float f) {   // cold paths only
    return __builtin_bit_cast(unsigned short, __float2bfloat16(f));
}

// ---------------------------------------------------------------------------
// Prep (R10-proven): fouriercoeffs [2][64][256][300] f32 -> WP bf16 4KB
// chunks per (ib, g). In-chunk byte = q*1024 + j*16 + (il&3)*4 + t*2.
// HBM-roofline-bound already (~15.6us for 98MB of traffic).
// ---------------------------------------------------------------------------
__global__ __launch_bounds__(256) void fkan_prep(const float* __restrict__ fc,
                                                 char* __restrict__ wp) {
    __shared__ alignas(16) char lds[32768];
    const int blk = blockIdx.x;
    const int ib  = blk & 15;          // i-split 0..15
    const int gb  = blk >> 4;          // 0..37
    const int g0  = gb * 8;
    const int G   = (gb == 37) ? 4 : 8;   // 300 = 37*8 + 4
    const int q   = threadIdx.x >> 6;     // wave = il quad
    const int j   = threadIdx.x & 63;     // lane = output col

    float vals[2][4][8];
    #pragma unroll
    for (int t = 0; t < 2; ++t) {
        #pragma unroll
        for (int e = 0; e < 4; ++e) {
            const float* src = fc + (((size_t)t * ODIM + j) * IDIM
                                     + (ib * 16 + q * 4 + e)) * GRIDN + g0;
            float4 lo = *(const float4*)(src);
            vals[t][e][0] = lo.x; vals[t][e][1] = lo.y;
            vals[t][e][2] = lo.z; vals[t][e][3] = lo.w;
            if (G == 8) {
                float4 hi = *(const float4*)(src + 4);
                vals[t][e][4] = hi.x; vals[t][e][5] = hi.y;
                vals[t][e][6] = hi.z; vals[t][e][7] = hi.w;
            }
        }
    }
    #pragma unroll
    for (int g = 0; g < 8; ++g) {
        if (g < 4 || G == 8) {
            uint4v dw;
            #pragma unroll
            for (int e = 0; e < 4; ++e)
                dw[e] = (unsigned)f2bf(vals[0][e][g]) | ((unsigned)f2bf(vals[1][e][g]) << 16);
            *(uint4v*)(lds + g * 4096 + q * 1024 + j * 16) = dw;
        }
    }
    __syncthreads();
    char* dst = wp + ((size_t)ib * GRIDN + g0) * 4096;
    for (int w = threadIdx.x * 16; w < G * 4096; w += 256 * 16)
        *(uint4v*)(dst + w) = *(const uint4v*)(lds + w);
}

// ---------------------------------------------------------------------------
// Main — R16's atomic-free barrier-free streaming structure, DE-FENCED:
// no s_setprio, no pk-asm (plain f32x2 ops). Block = (mt 0..63, kg 0..15):
// 32 output rows, 4 waves on SAME rows / DIFFERENT isplits. B-frags loaded
// straight from global as coalesced bf16x8 (1-deep prefetch). Epilogue: LDS
// 4-way K-reduce, plain coalesced stores to partials[kg][2048][64]; tiny
// reduce kernel sums 16 kg slices. Zero atomics (WRITE 8.2MB verified R16).
// ---------------------------------------------------------------------------
__global__ __launch_bounds__(256, 4) void fkan_main(const float* __restrict__ x,
                                                    const char* __restrict__ wp,
                                                    float* __restrict__ part) {
    __shared__ float red[4][32][64];             // 32KB reduce buffer

    const int bid    = blockIdx.x;               // 0..1023
    const int xcd    = bid & 7;
    const int within = bid >> 3;                 // 0..127
    const int kg     = xcd * 2 + (within & 1);   // 0..15 (XCD owns kg pair)
    const int mt     = within >> 1;              // 0..63 (32-row tile)
    const int iq     = kg >> 2;                  // isplit quad
    const int gq     = kg & 3;
    const int g_begin = gq * 75;

    const int tid  = threadIdx.x;
    const int wave = tid >> 6;
    const int lane = tid & 63;
    const int l31  = lane & 31;
    const int kgrp = lane >> 5;
    const int isplit = iq * 4 + wave;            // per-wave K-slice
    const int row  = mt * 32 + l31;              // A lane row (block-shared)

    // --- init 8 recurrence states, packed f32x2 ---
    f32x2 vc[4], vs[4], vbc[4], vbs[4];
    const float* xrow = x + (size_t)row * IDIM + isplit * 16;
    #pragma unroll
    for (int h = 0; h < 2; ++h) {
        const float4 xv4 = *(const float4*)(xrow + h * 8 + kgrp * 4);
        float xa[4] = {xv4.x, xv4.y, xv4.z, xv4.w};
        #pragma unroll
        for (int p = 0; p < 4; ++p) {
            const int ss = h * 4 + p;
            const float xv = xa[p];
            float sb, cb;
            __sincosf(xv, &sb, &cb);
            vbc[ss >> 1][ss & 1] = cb; vbs[ss >> 1][ss & 1] = sb;
            float s0 = sb, c0 = cb;
            if (g_begin != 0) __sincosf((float)(g_begin + 1) * xv, &s0, &c0);
            vc[ss >> 1][ss & 1] = c0; vs[ss >> 1][ss & 1] = s0;
        }
    }

    // per-lane fragment base inside chunk: q*1024 + j*16, q = kchunk*2 + kgrp
    const unsigned aq = (unsigned)kgrp * 1024 + (unsigned)l31 * 16;
    const char* curp = wp + ((size_t)(isplit * GRIDN + g_begin)) * 4096 + aq;

    // prologue: chunk 0 fragments straight to registers
    bf16x8 c0 = *(const bf16x8*)(curp);           // kc0, cols 0..31
    bf16x8 c1 = *(const bf16x8*)(curp + 512);     // kc0, cols 32..63
    bf16x8 c2 = *(const bf16x8*)(curp + 2048);    // kc1, cols 0..31
    bf16x8 c3 = *(const bf16x8*)(curp + 2560);    // kc1, cols 32..63

    f32x16 acc0 = {0,0,0,0,0,0,0,0,0,0,0,0,0,0,0,0};
    f32x16 acc1 = {0,0,0,0,0,0,0,0,0,0,0,0,0,0,0,0};

    #pragma unroll 2
    for (int it = 0; it < 75; ++it) {
        const char* np = curp + (it < 74 ? 4096 : 0);   // clamped tail dup
        const bf16x8 n0 = *(const bf16x8*)(np);
        const bf16x8 n1 = *(const bf16x8*)(np + 512);
        const bf16x8 n2 = *(const bf16x8*)(np + 2048);
        const bf16x8 n3 = *(const bf16x8*)(np + 2560);

        // A-frags: HW packed convert (the one proven asm win). dword p =
        // bf16(cos_p) | bf16(sin_p)<<16
        uint4v a1, a2;
        #pragma unroll
        for (int p = 0; p < 4; ++p) {
            const float c1f = vc[p >> 1][p & 1],       s1f = vs[p >> 1][p & 1];
            const float c2f = vc[2 + (p >> 1)][p & 1], s2f = vs[2 + (p >> 1)][p & 1];
            unsigned r1, r2;
            asm("v_cvt_pk_bf16_f32 %0, %1, %2" : "=v"(r1) : "v"(c1f), "v"(s1f));
            asm("v_cvt_pk_bf16_f32 %0, %1, %2" : "=v"(r2) : "v"(c2f), "v"(s2f));
            a1[p] = r1; a2[p] = r2;
        }
        const bf16x8 af1 = __builtin_bit_cast(bf16x8, a1);
        const bf16x8 af2 = __builtin_bit_cast(bf16x8, a2);
        acc0 = __builtin_amdgcn_mfma_f32_32x32x16_bf16(af1, c0, acc0, 0, 0, 0);
        acc1 = __builtin_amdgcn_mfma_f32_32x32x16_bf16(af1, c1, acc1, 0, 0, 0);
        acc0 = __builtin_amdgcn_mfma_f32_32x32x16_bf16(af2, c2, acc0, 0, 0, 0);
        acc1 = __builtin_amdgcn_mfma_f32_32x32x16_bf16(af2, c3, acc1, 0, 0, 0);
        // advance phases: plain f32x2 (compiler-scheduled; no asm fences)
        #pragma unroll
        for (int qq = 0; qq < 4; ++qq) {
            const f32x2 c = vc[qq], s = vs[qq];
            vc[qq] = c * vbc[qq] - s * vbs[qq];
            vs[qq] = s * vbc[qq] + c * vbs[qq];
        }
        c0 = n0; c1 = n1; c2 = n2; c3 = n3;
        curp = np;
    }

    // epilogue: 4-wave LDS K-reduce (waves hold different isplits, SAME rows)
    // D layout (32x32): col = lane&31, row = (r&3)+8*(r>>2)+4*kgrp
    #pragma unroll
    for (int r = 0; r < 16; ++r) {
        const int rbase = (r & 3) + 8 * (r >> 2) + 4 * kgrp;
        red[wave][rbase][l31]      = acc0[r];
        red[wave][rbase][32 + l31] = acc1[r];
    }
    __syncthreads();
    {
        const int row2 = wave * 8 + (lane >> 3);
        const int col0 = (lane & 7) * 8;
        f32x4 sA = *(const f32x4*)(&red[0][row2][col0]);
        f32x4 sB = *(const f32x4*)(&red[0][row2][col0 + 4]);
        #pragma unroll
        for (int w2 = 1; w2 < 4; ++w2) {
            sA += *(const f32x4*)(&red[w2][row2][col0]);
            sB += *(const f32x4*)(&red[w2][row2][col0 + 4]);
        }
        float* dst = part + ((size_t)kg * BATCH + mt * 32 + row2) * ODIM + col0;
        *(f32x4*)(dst)     = sA;
        *(f32x4*)(dst + 4) = sB;
    }
}

// ---------------------------------------------------------------------------
// Reduce: out[b,j] = sum over 16 kg partials. 131072 threads, coalesced.
// ---------------------------------------------------------------------------
__global__ __launch_bounds__(256) void fkan_reduce(const float* __restrict__ part,
                                                   float* __restrict__ out) {
    const int idx = blockIdx.x * 256 + threadIdx.x;   // 0..131071
    float s = 0.f;
    #pragma unroll
    for (int k = 0; k < 16; ++k)
        s += part[(size_t)k * (BATCH * ODIM) + idx];
    out[idx] = s;
}

// ---------------------------------------------------------------------------
// Fallback (ws too small): exact fp32, one thread per (b,j). Slow but correct.
// ---------------------------------------------------------------------------
__global__ __launch_bounds__(256) void fkan_naive(const float* __restrict__ x,
                                                  const float* __restrict__ fc,
                                                  float* __restrict__ out) {
    const int j = blockIdx.x >> 3;
    const int b = (blockIdx.x & 7) * 256 + threadIdx.x;
    const float* xr = x + (size_t)b * IDIM;
    float acc = 0.f;
    for (int i = 0; i < IDIM; ++i) {
        const float xv = xr[i];
        float sb, cb;
        __sincosf(xv, &sb, &cb);
        float c = cb, s = sb;
        const float* wc = fc + ((size_t)j * IDIM + i) * GRIDN;
        const float* ws = wc + (size_t)ODIM * IDIM * GRIDN;
        for (int g = 0; g < GRIDN; ++g) {
            acc += c * wc[g] + s * ws[g];
            const float cn = c * cb - s * sb;
            s = s * cb + c * sb;
            c = cn;
        }
    }
    out[(size_t)b * ODIM + j] = acc;
}

extern "C" void kernel_launch(void* const* d_in, const int* in_sizes, int n_in,
                              void* d_out, int out_size, void* d_ws, size_t ws_size,
                              hipStream_t stream) {
    const float* x  = (const float*)d_in[0];
    const float* fc = (const float*)d_in[1];
    float* out = (float*)d_out;
    constexpr size_t WPB  = 16ull * GRIDN * 4096;            // 19.66 MB weights
    constexpr size_t PART = 16ull * BATCH * ODIM * 4;        //  8.39 MB partials

    if (ws_size >= WPB + PART) {
        char*  wp   = (char*)d_ws;
        float* part = (float*)((char*)d_ws + WPB);
        fkan_prep<<<608, 256, 0, stream>>>(fc, wp);
        fkan_main<<<1024, 256, 0, stream>>>(x, wp, part);
        fkan_reduce<<<512, 256, 0, stream>>>(part, out);
    } else {
        fkan_naive<<<512, 256, 0, stream>>>(x, fc, out);
    }
}

// Round 18
// 77.932 us; speedup vs baseline: 1.3600x; 1.3600x over previous
//
#include <hip/hip_runtime.h>
#include <hip/hip_bf16.h>

#define BATCH 2048
#define IDIM  256
#define ODIM  64
#define GRIDN 300

typedef __bf16 bf16x8 __attribute__((ext_vector_type(8)));
typedef float  f32x16 __attribute__((ext_vector_type(16)));
typedef float  f32x4  __attribute__((ext_vector_type(4)));
typedef float  f32x2  __attribute__((ext_vector_type(2)));
typedef unsigned int uint4v __attribute__((ext_vector_type(4)));

#define AS1 __attribute__((address_space(1)))
#define AS3 __attribute__((address_space(3)))

// Session rules (all counter-verified this session):
//  - NO unions in hot paths (R4/R5/R6: scratch demotion, 0.3-1.6GB traffic)
//  - NO launch_bounds below natural allocation (R8: forced spill)
//  - NO __float2bfloat16 in hot loops (R9: ~5-inst software RNE) -> asm cvt_pk
//  - KEEP the setprio + pk-asm schedule pins (R17: removing them let the
//    scheduler sink the prefetch loads -> serialized latency, 58.5->89us)
__device__ __forceinline__ unsigned short f2bf(float f) {   // cold paths only
    return __builtin_bit_cast(unsigned short, __float2bfloat16(f));
}

// ---------------------------------------------------------------------------
// Prep (R10-proven): fouriercoeffs [2][64][256][300] f32 -> WP bf16 4KB
// chunks per (ib, g). In-chunk byte = q*1024 + j*16 + (il&3)*4 + t*2.
// Half-line reads are L2-recovered by the gb*16+ib block ordering (gb,gb+1
// for one ib land on the same XCD). ~15us, near its latency-bound floor.
// ---------------------------------------------------------------------------
__global__ __launch_bounds__(256) void fkan_prep(const float* __restrict__ fc,
                                                 char* __restrict__ wp) {
    __shared__ alignas(16) char lds[32768];
    const int blk = blockIdx.x;
    const int ib  = blk & 15;          // i-split 0..15
    const int gb  = blk >> 4;          // 0..37
    const int g0  = gb * 8;
    const int G   = (gb == 37) ? 4 : 8;   // 300 = 37*8 + 4
    const int q   = threadIdx.x >> 6;     // wave = il quad
    const int j   = threadIdx.x & 63;     // lane = output col

    float vals[2][4][8];
    #pragma unroll
    for (int t = 0; t < 2; ++t) {
        #pragma unroll
        for (int e = 0; e < 4; ++e) {
            const float* src = fc + (((size_t)t * ODIM + j) * IDIM
                                     + (ib * 16 + q * 4 + e)) * GRIDN + g0;
            float4 lo = *(const float4*)(src);
            vals[t][e][0] = lo.x; vals[t][e][1] = lo.y;
            vals[t][e][2] = lo.z; vals[t][e][3] = lo.w;
            if (G == 8) {
                float4 hi = *(const float4*)(src + 4);
                vals[t][e][4] = hi.x; vals[t][e][5] = hi.y;
                vals[t][e][6] = hi.z; vals[t][e][7] = hi.w;
            }
        }
    }
    #pragma unroll
    for (int g = 0; g < 8; ++g) {
        if (g < 4 || G == 8) {
            uint4v dw;
            #pragma unroll
            for (int e = 0; e < 4; ++e)
                dw[e] = (unsigned)f2bf(vals[0][e][g]) | ((unsigned)f2bf(vals[1][e][g]) << 16);
            *(uint4v*)(lds + g * 4096 + q * 1024 + j * 16) = dw;
        }
    }
    __syncthreads();
    char* dst = wp + ((size_t)ib * GRIDN + g0) * 4096;
    for (int w = threadIdx.x * 16; w < G * 4096; w += 256 * 16)
        *(uint4v*)(dst + w) = *(const uint4v*)(lds + w);
}

// ---------------------------------------------------------------------------
// Main — R16 VERBATIM (best measured: 58.5us, zero spill, zero atomics).
// Block = (mt 0..63, kg 0..15): 32 output rows, 4 waves on SAME rows with
// DIFFERENT isplits. Barrier-free streaming body: B-frags as coalesced
// bf16x8 global loads, 1-deep prefetch, HW cvt_pk A-frags, forced-pk
// recurrence, setprio MFMA brackets (schedule pins — see R17 lesson).
// Epilogue: 4-wave LDS K-reduce + plain coalesced stores to partials.
// ---------------------------------------------------------------------------
__global__ __launch_bounds__(256, 4) void fkan_main(const float* __restrict__ x,
                                                    const char* __restrict__ wp,
                                                    float* __restrict__ part) {
    __shared__ float red[4][32][64];             // 32KB reduce buffer

    const int bid    = blockIdx.x;               // 0..1023
    const int xcd    = bid & 7;
    const int within = bid >> 3;                 // 0..127
    const int kg     = xcd * 2 + (within & 1);   // 0..15 (XCD owns kg pair)
    const int mt     = within >> 1;              // 0..63 (32-row tile)
    const int iq     = kg >> 2;                  // isplit quad
    const int gq     = kg & 3;
    const int g_begin = gq * 75;

    const int tid  = threadIdx.x;
    const int wave = tid >> 6;
    const int lane = tid & 63;
    const int l31  = lane & 31;
    const int kgrp = lane >> 5;
    const int isplit = iq * 4 + wave;            // per-wave K-slice
    const int row  = mt * 32 + l31;              // A lane row (block-shared)

    // --- init 8 recurrence states, packed f32x2; vnbs = -vbs ---
    f32x2 vc[4], vs[4], vbc[4], vbs[4], vnbs[4];
    const float* xrow = x + (size_t)row * IDIM + isplit * 16;
    #pragma unroll
    for (int h = 0; h < 2; ++h) {
        const float4 xv4 = *(const float4*)(xrow + h * 8 + kgrp * 4);
        float xa[4] = {xv4.x, xv4.y, xv4.z, xv4.w};
        #pragma unroll
        for (int p = 0; p < 4; ++p) {
            const int ss = h * 4 + p;
            const float xv = xa[p];
            float sb, cb;
            __sincosf(xv, &sb, &cb);
            vbc[ss >> 1][ss & 1] = cb; vbs[ss >> 1][ss & 1] = sb;
            vnbs[ss >> 1][ss & 1] = -sb;
            float s0 = sb, c0 = cb;
            if (g_begin != 0) __sincosf((float)(g_begin + 1) * xv, &s0, &c0);
            vc[ss >> 1][ss & 1] = c0; vs[ss >> 1][ss & 1] = s0;
        }
    }

    // per-lane fragment base inside chunk: q*1024 + j*16, q = kchunk*2 + kgrp
    const unsigned aq = (unsigned)kgrp * 1024 + (unsigned)l31 * 16;
    const char* curp = wp + ((size_t)(isplit * GRIDN + g_begin)) * 4096 + aq;

    // prologue: chunk 0 fragments straight to registers
    bf16x8 c0 = *(const bf16x8*)(curp);           // kc0, cols 0..31
    bf16x8 c1 = *(const bf16x8*)(curp + 512);     // kc0, cols 32..63
    bf16x8 c2 = *(const bf16x8*)(curp + 2048);    // kc1, cols 0..31
    bf16x8 c3 = *(const bf16x8*)(curp + 2560);    // kc1, cols 32..63

    f32x16 acc0 = {0,0,0,0,0,0,0,0,0,0,0,0,0,0,0,0};
    f32x16 acc1 = {0,0,0,0,0,0,0,0,0,0,0,0,0,0,0,0};

    #pragma unroll 2
    for (int it = 0; it < 75; ++it) {
        const char* np = curp + (it < 74 ? 4096 : 0);   // clamped tail dup
        const bf16x8 n0 = *(const bf16x8*)(np);
        const bf16x8 n1 = *(const bf16x8*)(np + 512);
        const bf16x8 n2 = *(const bf16x8*)(np + 2048);
        const bf16x8 n3 = *(const bf16x8*)(np + 2560);

        uint4v a1, a2;
        #pragma unroll
        for (int p = 0; p < 4; ++p) {
            const float c1f = vc[p >> 1][p & 1],       s1f = vs[p >> 1][p & 1];
            const float c2f = vc[2 + (p >> 1)][p & 1], s2f = vs[2 + (p >> 1)][p & 1];
            unsigned r1, r2;
            asm("v_cvt_pk_bf16_f32 %0, %1, %2" : "=v"(r1) : "v"(c1f), "v"(s1f));
            asm("v_cvt_pk_bf16_f32 %0, %1, %2" : "=v"(r2) : "v"(c2f), "v"(s2f));
            a1[p] = r1; a2[p] = r2;
        }
        const bf16x8 af1 = __builtin_bit_cast(bf16x8, a1);
        const bf16x8 af2 = __builtin_bit_cast(bf16x8, a2);
        __builtin_amdgcn_s_setprio(1);
        acc0 = __builtin_amdgcn_mfma_f32_32x32x16_bf16(af1, c0, acc0, 0, 0, 0);
        acc1 = __builtin_amdgcn_mfma_f32_32x32x16_bf16(af1, c1, acc1, 0, 0, 0);
        acc0 = __builtin_amdgcn_mfma_f32_32x32x16_bf16(af2, c2, acc0, 0, 0, 0);
        acc1 = __builtin_amdgcn_mfma_f32_32x32x16_bf16(af2, c3, acc1, 0, 0, 0);
        __builtin_amdgcn_s_setprio(0);
        #pragma unroll
        for (int qq = 0; qq < 4; ++qq) {
            f32x2 t, u, cn, sn;
            asm("v_pk_mul_f32 %0, %1, %2" : "=v"(t) : "v"(vs[qq]), "v"(vnbs[qq]));
            asm("v_pk_mul_f32 %0, %1, %2" : "=v"(u) : "v"(vc[qq]), "v"(vbs[qq]));
            asm("v_pk_fma_f32 %0, %1, %2, %3" : "=v"(cn) : "v"(vc[qq]), "v"(vbc[qq]), "v"(t));
            asm("v_pk_fma_f32 %0, %1, %2, %3" : "=v"(sn) : "v"(vs[qq]), "v"(vbc[qq]), "v"(u));
            vc[qq] = cn; vs[qq] = sn;
        }
        c0 = n0; c1 = n1; c2 = n2; c3 = n3;
        curp = np;
    }

    // epilogue: 4-wave LDS K-reduce (waves hold different isplits, SAME rows)
    // D layout (32x32): col = lane&31, row = (r&3)+8*(r>>2)+4*kgrp
    #pragma unroll
    for (int r = 0; r < 16; ++r) {
        const int rbase = (r & 3) + 8 * (r >> 2) + 4 * kgrp;
        red[wave][rbase][l31]      = acc0[r];
        red[wave][rbase][32 + l31] = acc1[r];
    }
    __syncthreads();
    {
        const int row2 = wave * 8 + (lane >> 3);
        const int col0 = (lane & 7) * 8;
        f32x4 sA = *(const f32x4*)(&red[0][row2][col0]);
        f32x4 sB = *(const f32x4*)(&red[0][row2][col0 + 4]);
        #pragma unroll
        for (int w2 = 1; w2 < 4; ++w2) {
            sA += *(const f32x4*)(&red[w2][row2][col0]);
            sB += *(const f32x4*)(&red[w2][row2][col0 + 4]);
        }
        float* dst = part + ((size_t)kg * BATCH + mt * 32 + row2) * ODIM + col0;
        *(f32x4*)(dst)     = sA;
        *(f32x4*)(dst + 4) = sB;
    }
}

// ---------------------------------------------------------------------------
// Reduce (vectorized): out[0:131072] = sum of 16 kg partial slices.
// 32768 threads x f32x4: 16B/lane coalesced reads/writes, 16-way ILP.
// ---------------------------------------------------------------------------
__global__ __launch_bounds__(256) void fkan_reduce(const float* __restrict__ part,
                                                   float* __restrict__ out) {
    const int idx4 = (blockIdx.x * 256 + threadIdx.x) * 4;   // 0..131068
    f32x4 s = *(const f32x4*)(part + idx4);
    #pragma unroll
    for (int k = 1; k < 16; ++k)
        s += *(const f32x4*)(part + (size_t)k * (BATCH * ODIM) + idx4);
    *(f32x4*)(out + idx4) = s;
}

// ---------------------------------------------------------------------------
// Fallback (ws too small): exact fp32, one thread per (b,j). Slow but correct.
// ---------------------------------------------------------------------------
__global__ __launch_bounds__(256) void fkan_naive(const float* __restrict__ x,
                                                  const float* __restrict__ fc,
                                                  float* __restrict__ out) {
    const int j = blockIdx.x >> 3;
    const int b = (blockIdx.x & 7) * 256 + threadIdx.x;
    const float* xr = x + (size_t)b * IDIM;
    float acc = 0.f;
    for (int i = 0; i < IDIM; ++i) {
        const float xv = xr[i];
        float sb, cb;
        __sincosf(xv, &sb, &cb);
        float c = cb, s = sb;
        const float* wc = fc + ((size_t)j * IDIM + i) * GRIDN;
        const float* ws = wc + (size_t)ODIM * IDIM * GRIDN;
        for (int g = 0; g < GRIDN; ++g) {
            acc += c * wc[g] + s * ws[g];
            const float cn = c * cb - s * sb;
            s = s * cb + c * sb;
            c = cn;
        }
    }
    out[(size_t)b * ODIM + j] = acc;
}

extern "C" void kernel_launch(void* const* d_in, const int* in_sizes, int n_in,
                              void* d_out, int out_size, void* d_ws, size_t ws_size,
                              hipStream_t stream) {
    const float* x  = (const float*)d_in[0];
    const float* fc = (const float*)d_in[1];
    float* out = (float*)d_out;
    constexpr size_t WPB  = 16ull * GRIDN * 4096;            // 19.66 MB weights
    constexpr size_t PART = 16ull * BATCH * ODIM * 4;        //  8.39 MB partials

    if (ws_size >= WPB + PART) {
        char*  wp   = (char*)d_ws;
        float* part = (float*)((char*)d_ws + WPB);
        fkan_prep<<<608, 256, 0, stream>>>(fc, wp);
        fkan_main<<<1024, 256, 0, stream>>>(x, wp, part);
        fkan_reduce<<<128, 256, 0, stream>>>(part, out);
    } else {
        fkan_naive<<<512, 256, 0, stream>>>(x, fc, out);
    }
}

// Round 20
// 77.540 us; speedup vs baseline: 1.3669x; 1.0050x over previous
//
#include <hip/hip_runtime.h>
#include <hip/hip_bf16.h>

#define BATCH 2048
#define IDIM  256
#define ODIM  64
#define GRIDN 300

typedef __bf16 bf16x8 __attribute__((ext_vector_type(8)));
typedef float  f32x16 __attribute__((ext_vector_type(16)));
typedef float  f32x4  __attribute__((ext_vector_type(4)));
typedef float  f32x2  __attribute__((ext_vector_type(2)));
typedef unsigned int uint4v __attribute__((ext_vector_type(4)));

#define AS1 __attribute__((address_space(1)))
#define AS3 __attribute__((address_space(3)))

// Session rules (all counter-verified):
//  - NO unions in hot paths (R4/R5/R6: scratch demotion, 0.3-1.6GB traffic)
//  - NO launch_bounds below natural allocation (R8: forced spill)
//  - NO __float2bfloat16 in hot loops (R9: software RNE) -> asm cvt_pk
//  - KEEP setprio + pk-asm schedule pins (R17: removal sank prefetch, +52%)
//  - NO register growth past ~96 (R19: 2-deep prefetch @ ~144 regs broke
//    correctness under the (256,4) 128-reg cap with inline-asm operands)
__device__ __forceinline__ unsigned short f2bf(float f) {   // cold paths only
    return __builtin_bit_cast(unsigned short, __float2bfloat16(f));
}

// ---------------------------------------------------------------------------
// Prep (R10-proven): fouriercoeffs [2][64][256][300] f32 -> WP bf16 4KB
// chunks per (ib, g). In-chunk byte = q*1024 + j*16 + (il&3)*4 + t*2.
// ---------------------------------------------------------------------------
__global__ __launch_bounds__(256) void fkan_prep(const float* __restrict__ fc,
                                                 char* __restrict__ wp) {
    __shared__ alignas(16) char lds[32768];
    const int blk = blockIdx.x;
    const int ib  = blk & 15;          // i-split 0..15
    const int gb  = blk >> 4;          // 0..37
    const int g0  = gb * 8;
    const int G   = (gb == 37) ? 4 : 8;   // 300 = 37*8 + 4
    const int q   = threadIdx.x >> 6;     // wave = il quad
    const int j   = threadIdx.x & 63;     // lane = output col

    float vals[2][4][8];
    #pragma unroll
    for (int t = 0; t < 2; ++t) {
        #pragma unroll
        for (int e = 0; e < 4; ++e) {
            const float* src = fc + (((size_t)t * ODIM + j) * IDIM
                                     + (ib * 16 + q * 4 + e)) * GRIDN + g0;
            float4 lo = *(const float4*)(src);
            vals[t][e][0] = lo.x; vals[t][e][1] = lo.y;
            vals[t][e][2] = lo.z; vals[t][e][3] = lo.w;
            if (G == 8) {
                float4 hi = *(const float4*)(src + 4);
                vals[t][e][4] = hi.x; vals[t][e][5] = hi.y;
                vals[t][e][6] = hi.z; vals[t][e][7] = hi.w;
            }
        }
    }
    #pragma unroll
    for (int g = 0; g < 8; ++g) {
        if (g < 4 || G == 8) {
            uint4v dw;
            #pragma unroll
            for (int e = 0; e < 4; ++e)
                dw[e] = (unsigned)f2bf(vals[0][e][g]) | ((unsigned)f2bf(vals[1][e][g]) << 16);
            *(uint4v*)(lds + g * 4096 + q * 1024 + j * 16) = dw;
        }
    }
    __syncthreads();
    char* dst = wp + ((size_t)ib * GRIDN + g0) * 4096;
    for (int w = threadIdx.x * 16; w < G * 4096; w += 256 * 16)
        *(uint4v*)(dst + w) = *(const uint4v*)(lds + w);
}

// ---------------------------------------------------------------------------
// Main — R16/R18 VERBATIM (best verified: 58.5us main, zero spill, zero
// atomics, absmax 0.0156). Block = (mt 0..63, kg 0..15): 32 output rows,
// 4 waves on SAME rows with DIFFERENT isplits. Barrier-free streaming:
// B-frags as coalesced bf16x8 global loads, 1-deep prefetch, HW cvt_pk
// A-frags, forced-pk recurrence, setprio MFMA brackets (schedule pins).
// Epilogue: 4-wave LDS K-reduce + plain coalesced stores to partials.
// ---------------------------------------------------------------------------
__global__ __launch_bounds__(256, 4) void fkan_main(const float* __restrict__ x,
                                                    const char* __restrict__ wp,
                                                    float* __restrict__ part) {
    __shared__ float red[4][32][64];             // 32KB reduce buffer

    const int bid    = blockIdx.x;               // 0..1023
    const int xcd    = bid & 7;
    const int within = bid >> 3;                 // 0..127
    const int kg     = xcd * 2 + (within & 1);   // 0..15 (XCD owns kg pair)
    const int mt     = within >> 1;              // 0..63 (32-row tile)
    const int iq     = kg >> 2;                  // isplit quad
    const int gq     = kg & 3;
    const int g_begin = gq * 75;

    const int tid  = threadIdx.x;
    const int wave = tid >> 6;
    const int lane = tid & 63;
    const int l31  = lane & 31;
    const int kgrp = lane >> 5;
    const int isplit = iq * 4 + wave;            // per-wave K-slice
    const int row  = mt * 32 + l31;              // A lane row (block-shared)

    // --- init 8 recurrence states, packed f32x2; vnbs = -vbs ---
    f32x2 vc[4], vs[4], vbc[4], vbs[4], vnbs[4];
    const float* xrow = x + (size_t)row * IDIM + isplit * 16;
    #pragma unroll
    for (int h = 0; h < 2; ++h) {
        const float4 xv4 = *(const float4*)(xrow + h * 8 + kgrp * 4);
        float xa[4] = {xv4.x, xv4.y, xv4.z, xv4.w};
        #pragma unroll
        for (int p = 0; p < 4; ++p) {
            const int ss = h * 4 + p;
            const float xv = xa[p];
            float sb, cb;
            __sincosf(xv, &sb, &cb);
            vbc[ss >> 1][ss & 1] = cb; vbs[ss >> 1][ss & 1] = sb;
            vnbs[ss >> 1][ss & 1] = -sb;
            float s0 = sb, c0 = cb;
            if (g_begin != 0) __sincosf((float)(g_begin + 1) * xv, &s0, &c0);
            vc[ss >> 1][ss & 1] = c0; vs[ss >> 1][ss & 1] = s0;
        }
    }

    // per-lane fragment base inside chunk: q*1024 + j*16, q = kchunk*2 + kgrp
    const unsigned aq = (unsigned)kgrp * 1024 + (unsigned)l31 * 16;
    const char* curp = wp + ((size_t)(isplit * GRIDN + g_begin)) * 4096 + aq;

    // prologue: chunk 0 fragments straight to registers
    bf16x8 c0 = *(const bf16x8*)(curp);           // kc0, cols 0..31
    bf16x8 c1 = *(const bf16x8*)(curp + 512);     // kc0, cols 32..63
    bf16x8 c2 = *(const bf16x8*)(curp + 2048);    // kc1, cols 0..31
    bf16x8 c3 = *(const bf16x8*)(curp + 2560);    // kc1, cols 32..63

    f32x16 acc0 = {0,0,0,0,0,0,0,0,0,0,0,0,0,0,0,0};
    f32x16 acc1 = {0,0,0,0,0,0,0,0,0,0,0,0,0,0,0,0};

    #pragma unroll 2
    for (int it = 0; it < 75; ++it) {
        const char* np = curp + (it < 74 ? 4096 : 0);   // clamped tail dup
        const bf16x8 n0 = *(const bf16x8*)(np);
        const bf16x8 n1 = *(const bf16x8*)(np + 512);
        const bf16x8 n2 = *(const bf16x8*)(np + 2048);
        const bf16x8 n3 = *(const bf16x8*)(np + 2560);

        uint4v a1, a2;
        #pragma unroll
        for (int p = 0; p < 4; ++p) {
            const float c1f = vc[p >> 1][p & 1],       s1f = vs[p >> 1][p & 1];
            const float c2f = vc[2 + (p >> 1)][p & 1], s2f = vs[2 + (p >> 1)][p & 1];
            unsigned r1, r2;
            asm("v_cvt_pk_bf16_f32 %0, %1, %2" : "=v"(r1) : "v"(c1f), "v"(s1f));
            asm("v_cvt_pk_bf16_f32 %0, %1, %2" : "=v"(r2) : "v"(c2f), "v"(s2f));
            a1[p] = r1; a2[p] = r2;
        }
        const bf16x8 af1 = __builtin_bit_cast(bf16x8, a1);
        const bf16x8 af2 = __builtin_bit_cast(bf16x8, a2);
        __builtin_amdgcn_s_setprio(1);
        acc0 = __builtin_amdgcn_mfma_f32_32x32x16_bf16(af1, c0, acc0, 0, 0, 0);
        acc1 = __builtin_amdgcn_mfma_f32_32x32x16_bf16(af1, c1, acc1, 0, 0, 0);
        acc0 = __builtin_amdgcn_mfma_f32_32x32x16_bf16(af2, c2, acc0, 0, 0, 0);
        acc1 = __builtin_amdgcn_mfma_f32_32x32x16_bf16(af2, c3, acc1, 0, 0, 0);
        __builtin_amdgcn_s_setprio(0);
        #pragma unroll
        for (int qq = 0; qq < 4; ++qq) {
            f32x2 t, u, cn, sn;
            asm("v_pk_mul_f32 %0, %1, %2" : "=v"(t) : "v"(vs[qq]), "v"(vnbs[qq]));
            asm("v_pk_mul_f32 %0, %1, %2" : "=v"(u) : "v"(vc[qq]), "v"(vbs[qq]));
            asm("v_pk_fma_f32 %0, %1, %2, %3" : "=v"(cn) : "v"(vc[qq]), "v"(vbc[qq]), "v"(t));
            asm("v_pk_fma_f32 %0, %1, %2, %3" : "=v"(sn) : "v"(vs[qq]), "v"(vbc[qq]), "v"(u));
            vc[qq] = cn; vs[qq] = sn;
        }
        c0 = n0; c1 = n1; c2 = n2; c3 = n3;
        curp = np;
    }

    // epilogue: 4-wave LDS K-reduce (waves hold different isplits, SAME rows)
    // D layout (32x32): col = lane&31, row = (r&3)+8*(r>>2)+4*kgrp
    #pragma unroll
    for (int r = 0; r < 16; ++r) {
        const int rbase = (r & 3) + 8 * (r >> 2) + 4 * kgrp;
        red[wave][rbase][l31]      = acc0[r];
        red[wave][rbase][32 + l31] = acc1[r];
    }
    __syncthreads();
    {
        const int row2 = wave * 8 + (lane >> 3);
        const int col0 = (lane & 7) * 8;
        f32x4 sA = *(const f32x4*)(&red[0][row2][col0]);
        f32x4 sB = *(const f32x4*)(&red[0][row2][col0 + 4]);
        #pragma unroll
        for (int w2 = 1; w2 < 4; ++w2) {
            sA += *(const f32x4*)(&red[w2][row2][col0]);
            sB += *(const f32x4*)(&red[w2][row2][col0 + 4]);
        }
        float* dst = part + ((size_t)kg * BATCH + mt * 32 + row2) * ODIM + col0;
        *(f32x4*)(dst)     = sA;
        *(f32x4*)(dst + 4) = sB;
    }
}

// ---------------------------------------------------------------------------
// Reduce (vectorized): out[0:131072] = sum of 16 kg partial slices.
// ---------------------------------------------------------------------------
__global__ __launch_bounds__(256) void fkan_reduce(const float* __restrict__ part,
                                                   float* __restrict__ out) {
    const int idx4 = (blockIdx.x * 256 + threadIdx.x) * 4;   // 0..131068
    f32x4 s = *(const f32x4*)(part + idx4);
    #pragma unroll
    for (int k = 1; k < 16; ++k)
        s += *(const f32x4*)(part + (size_t)k * (BATCH * ODIM) + idx4);
    *(f32x4*)(out + idx4) = s;
}

// ---------------------------------------------------------------------------
// Fallback (ws too small): exact fp32, one thread per (b,j). Slow but correct.
// ---------------------------------------------------------------------------
__global__ __launch_bounds__(256) void fkan_naive(const float* __restrict__ x,
                                                  const float* __restrict__ fc,
                                                  float* __restrict__ out) {
    const int j = blockIdx.x >> 3;
    const int b = (blockIdx.x & 7) * 256 + threadIdx.x;
    const float* xr = x + (size_t)b * IDIM;
    float acc = 0.f;
    for (int i = 0; i < IDIM; ++i) {
        const float xv = xr[i];
        float sb, cb;
        __sincosf(xv, &sb, &cb);
        float c = cb, s = sb;
        const float* wc = fc + ((size_t)j * IDIM + i) * GRIDN;
        const float* ws = wc + (size_t)ODIM * IDIM * GRIDN;
        for (int g = 0; g < GRIDN; ++g) {
            acc += c * wc[g] + s * ws[g];
            const float cn = c * cb - s * sb;
            s = s * cb + c * sb;
            c = cn;
        }
    }
    out[(size_t)b * ODIM + j] = acc;
}

extern "C" void kernel_launch(void* const* d_in, const int* in_sizes, int n_in,
                              void* d_out, int out_size, void* d_ws, size_t ws_size,
                              hipStream_t stream) {
    const float* x  = (const float*)d_in[0];
    const float* fc = (const float*)d_in[1];
    float* out = (float*)d_out;
    constexpr size_t WPB  = 16ull * GRIDN * 4096;            // 19.66 MB weights
    constexpr size_t PART = 16ull * BATCH * ODIM * 4;        //  8.39 MB partials

    if (ws_size >= WPB + PART) {
        char*  wp   = (char*)d_ws;
        float* part = (float*)((char*)d_ws + WPB);
        fkan_prep<<<608, 256, 0, stream>>>(fc, wp);
        fkan_main<<<1024, 256, 0, stream>>>(x, wp, part);
        fkan_reduce<<<128, 256, 0, stream>>>(part, out);
    } else {
        fkan_naive<<<512, 256, 0, stream>>>(x, fc, out);
    }
}